// Round 6
// baseline (383.854 us; speedup 1.0000x reference)
//
#include <hip/hip_runtime.h>
#include <hip/hip_cooperative_groups.h>
#include <math.h>

namespace cg = cooperative_groups;

#define NSs 6
#define NTs 4
#define Bb  2
#define Nn  32
#define Hh  768
#define Ww  768
#define Rr  28
#define Cch 10
#define NCH 38
#define HW  (Hh*Ww)
#define NEGD (-100.0)
#define NKEY (Nn*Cch + NSs)        // 326: 320 inst-hist keys + 6 stuff counts
#define WS_LUT (Bb*NKEY*256)       // 166912: hist table ws[b*326+k][256], then LUT [Bb][38]

struct InstP {
  int y0, x0, y1r, x1r;   // inst box [y0,y1r) x [x0,x1r)
  int ys, ye, xs, xe;     // mask box
  float sc_y, sc_x;       // 28.f/h, 28.f/w
  int tc;                 // NS + cls
  int mskoff;             // offset of selected 28x28 mask
};

__device__ __forceinline__ double sigd(double x) { return 1.0 / (1.0 + exp(-x)); }

// proven fuse+argmax core (bit-exact since R1). ch[] constant-indexed after inline.
__device__ __forceinline__ int fuse_px(
    int y, int x, const float (&ch)[Cch], unsigned rel,
    const InstP* __restrict__ spar, const float* __restrict__ roi,
    double EPS, int* smp_out)
{
  int smp = 0; float smv = ch[0];
#pragma unroll
  for (int c = 1; c < Cch; c++) if (ch[c] > smv) { smv = ch[c]; smp = c; }
  *smp_out = smp;

  double m = (double)ch[0]; int pidx = 0;
#pragma unroll
  for (int c = 1; c < NSs; c++) { double v = (double)ch[c]; if (v > m) { m = v; pidx = c; } }

  int next_ch = NSs;
  while (rel) {
    int n = __ffs(rel) - 1; rel &= rel - 1;
    int chn_ = NSs + n;
    if (chn_ > next_ch && EPS > m) { m = EPS; pidx = next_ch; }
    next_ch = chn_ + 1;
    const InstP p = spar[n];
    bool in_i = (y >= p.y0) && (y < p.y1r) && (x >= p.x0) && (x < p.x1r);
    bool in_m = (y >= p.ys) && (y < p.ye)  && (x >= p.xs) && (x < p.xe);
    bool in_any = in_i || in_m;
    if (__any(in_any)) {            // wave lanes = contiguous 64-px window
      if (in_any) {
        // select chain (NOT ch[p.tc]): dynamic reg-array indexing -> scratch
        int tcl = p.tc;
        float tl = (tcl == 6) ? ch[6] : (tcl == 7) ? ch[7] : (tcl == 8) ? ch[8] : ch[9];
        double iv = in_i ? (double)tl : NEGD;
        double mv = NEGD;
        if (in_m) {
          double syv = ((double)(y - p.y0) + 0.5) * (double)p.sc_y - 0.5;
          double sxv = ((double)(x - p.x0) + 0.5) * (double)p.sc_x - 0.5;
          syv = fmin(fmax(syv, 0.0), 27.0);
          sxv = fmin(fmax(sxv, 0.0), 27.0);
          int iy0 = (int)syv, ix0 = (int)sxv;
          int iy1 = min(iy0 + 1, 27), ix1 = min(ix0 + 1, 27);
          double wy = syv - (double)iy0, wx = sxv - (double)ix0;
          const float* mp = roi + p.mskoff;
          double m00 = (double)mp[iy0*Rr + ix0];
          double m01 = (double)mp[iy0*Rr + ix1];
          double m10 = (double)mp[iy1*Rr + ix0];
          double m11 = (double)mp[iy1*Rr + ix1];
          double c0 = m00*(1.0 - wy) + m10*wy;
          double c1 = m01*(1.0 - wy) + m11*wy;
          mv = c0*(1.0 - wx) + c1*wx;
        }
        double s2 = iv + mv;
        // prune: val = s*s2, s in (0,2]; if fmax(2*s2,0) <= m, val>m impossible
        if (fmax(2.0*s2, 0.0) > m) {
          double val = (sigd(iv) + sigd(mv)) * s2;
          if (val > m) { m = val; pidx = chn_; }
        }
      } else {
        if (EPS > m) { m = EPS; pidx = chn_; }
      }
    } else {
      if (EPS > m) { m = EPS; pidx = chn_; }
    }
  }
  if (next_ch < NCH && EPS > m) { m = EPS; pidx = next_ch; }
  return pidx;
}

__device__ __forceinline__ void setup_inst(
    int b, int tid, const float* __restrict__ bbx, const int* __restrict__ cls,
    InstP* spar)
{
  const int n = tid;
  const float* bbp = bbx + ((size_t)b*Nn + n)*4;
  float f0 = bbp[0], f1 = bbp[1], f2 = bbp[2], f3 = bbp[3];
  int y0 = (int)floorf(f0), x0 = (int)floorf(f1);
  int y1 = (int)floorf(f2), x1 = (int)floorf(f3);
  int y1r = (int)(rintf(f2) + 1.0f);   // jnp.round = half-to-even
  int x1r = (int)(rintf(f3) + 1.0f);
  float hh = fmaxf((float)(y1 - y0 + 1), 1.0f);
  float wd = fmaxf((float)(x1 - x0 + 1), 1.0f);
  InstP p;
  p.y0 = y0; p.x0 = x0; p.y1r = y1r; p.x1r = x1r;
  p.ys = max(y0, 0); p.ye = min(y1 + 1, Hh);
  p.xs = max(x0, 0); p.xe = min(x1 + 1, Ww);
  p.sc_y = 28.0f / hh; p.sc_x = 28.0f / wd;
  int cl = cls[b*Nn + n];
  p.tc = NSs + cl;
  p.mskoff = (((b*Nn + n)*NTs) + cl)*Rr*Rr;
  spar[n] = p;
}

// ============ single cooperative kernel: fuse -> post -> remap ============
// 512 blocks = 2 batches x 256 row-triples (3 full rows each), 256 thr x 9 px.
// Needs only 2 blocks/CU co-residency; validated host-side before launch.
__global__ __launch_bounds__(256, 2) void k_all(
    const float* __restrict__ sem, const float* __restrict__ roi,
    const float* __restrict__ bbx, const int* __restrict__ cls,
    int* __restrict__ out, int* __restrict__ ws)
{
  __shared__ InstP spar[Nn];
  __shared__ int s_all[NKEY];
  __shared__ unsigned s_relrow[3];
  __shared__ unsigned char s_pidx8[3*Ww];
  __shared__ int s_red[Bb*NKEY];
  __shared__ int s_spc[Bb][NSs];
  __shared__ int s_pcs[Bb][40];
  __shared__ int slut[NCH];

  cg::grid_group grid = cg::this_grid();

  const int bid = blockIdx.x;
  const int b   = bid >> 8;
  const int j   = bid & 255;     // slot within batch
  const int y0b = j * 3;
  const int tid = threadIdx.x;

  if (tid < 3) s_relrow[tid] = 0u;   // wave 0, before wave-0 atomicOr: program order
  for (int i = tid; i < NKEY; i += 256) s_all[i] = 0;
  if (tid < Nn) {
    setup_inst(b, tid, bbx, cls, spar);
    const InstP p = spar[tid];
#pragma unroll
    for (int r = 0; r < 3; r++) {
      int y = y0b + r;
      bool rowi = (y >= p.y0) && (y < p.y1r);
      bool rowm = (y >= p.ys) && (y < p.ye);
      if (rowi || rowm) atomicOr(&s_relrow[r], 1u << tid);
    }
  }
  __syncthreads();

  const double EPS = (sigd(NEGD) + sigd(NEGD)) * (NEGD + NEGD);
  const float* base = sem + (size_t)b*Cch*HW + (size_t)y0b*Ww;
  unsigned rel[3];
#pragma unroll
  for (int r = 0; r < 3; r++) rel[r] = s_relrow[r];

  float cur[3][Cch], nxt[3][Cch];
#pragma unroll
  for (int r = 0; r < 3; r++)
#pragma unroll
    for (int c = 0; c < Cch; c++) cur[r][c] = base[(size_t)c*HW + (size_t)r*Ww + tid];

  for (int ck = 0; ck < 3; ck++) {
    const int x = ck*256 + tid;
    if (ck < 2) {
#pragma unroll
      for (int r = 0; r < 3; r++)
#pragma unroll
        for (int c = 0; c < Cch; c++) nxt[r][c] = base[(size_t)c*HW + (size_t)r*Ww + x + 256];
    }
#pragma unroll
    for (int r = 0; r < 3; r++) {
      int smp;
      int pidx = fuse_px(y0b + r, x, cur[r], rel[r], spar, roi, EPS, &smp);
      s_pidx8[r*Ww + x] = (unsigned char)pidx;
      int key = (pidx >= NSs) ? ((pidx - NSs)*Cch + smp) : (Nn*Cch + pidx);
      atomicAdd(&s_all[key], 1);
    }
    if (ck < 2) {
#pragma unroll
      for (int r = 0; r < 3; r++)
#pragma unroll
        for (int c = 0; c < Cch; c++) cur[r][c] = nxt[r][c];
    }
  }
  __syncthreads();
  // per-block transposed hist write: no atomics, no pre-zeroing (every slot written)
  for (int i = tid; i < NKEY; i += 256) ws[(b*NKEY + i)*256 + j] = s_all[i];
  __threadfence();
  grid.sync();

  // ---- phase 2: block 0 reduces hist + computes LUT/tail (wave-parallel) ----
  if (bid == 0) {
    const int w = tid >> 6, lane = tid & 63;
    for (int k = w; k < Bb*NKEY; k += 4) {       // 652 = 4*163: uniform trip count
      int s = 0;
#pragma unroll
      for (int q = 0; q < 4; q++) s += ws[k*256 + q*64 + lane];
#pragma unroll
      for (int off = 32; off; off >>= 1) s += __shfl_down(s, off, 64);
      if (lane == 0) s_red[k] = s;
    }
    __syncthreads();
    const int b2 = w;                 // wave 0 = batch 0, wave 1 = batch 1
    const bool bv = b2 < Bb;
    const bool act = bv && (lane < Nn);
    if (bv && lane < NSs) s_spc[b2][lane] = s_red[b2*NKEY + Nn*Cch + lane];
    __syncthreads();
    int total = 0, mi = 0, mx = -1, tmpv = 0;
    bool br2f = false, keptf = false;
    if (act) {
      const int* hb = &s_red[b2*NKEY + lane*Cch];
#pragma unroll
      for (int c = 0; c < Cch; c++) { int v = hb[c]; total += v; if (v > mx) { mx = v; mi = c; } }
      tmpv = cls[b2*Nn + lane] + NSs;
      bool present = total > 0;
      bool b1 = (mi == tmpv);
      br2f  = (!b1) && (2*mx >= total) && (mi < NSs) && present;
      keptf = present && !br2f;
      if (br2f) atomicAdd(&s_spc[b2][mi], total);
    }
    __syncthreads();
    bool pred6 = bv && (lane < NSs) && (s_spc[b2 & 1][lane] > 0);
    unsigned mask6 = (unsigned)(__ballot(pred6) & 0x3Full);
    int nstuff = __popc(mask6);
    unsigned kmask = (unsigned)(__ballot(act && keptf) & 0xFFFFFFFFull);
    int nk = __popc(kmask);
    int vlen = 1 + nstuff + nk;

    if (bv && lane < NSs)
      ws[WS_LUT + b2*NCH + lane] = __popc(mask6 & ((1u << lane) - 1)) + 1;  // absent: unused
    if (act) {
      int rk  = __popc(kmask & ((1u << lane) - 1));
      int srk = __popc(mask6 & ((1u << mi) - 1));
      ws[WS_LUT + b2*NCH + NSs + lane] = keptf ? (1 + nstuff + rk) : (br2f ? srk + 1 : 0);
    }
    if (bv && lane < 39) s_pcs[b2][lane] = -1;
    __syncthreads();
    if (bv && lane == 0) s_pcs[b2][0] = 255;
    if (pred6) s_pcs[b2][1 + __popc(mask6 & ((1u << lane) - 1))] = lane;
    if (act && keptf) s_pcs[b2][1 + nstuff + __popc(kmask & ((1u << lane) - 1))] = tmpv;
    __syncthreads();
    int* pc = out + (size_t)Bb*HW;       // po_cls   [Bb][39]
    int* ic = pc + Bb*39;                // iscrowd  [Bb][39]
    int* vl = ic + Bb*39;                // valid_len[Bb]
    if (bv && lane < 39) {
      pc[b2*39 + lane] = s_pcs[b2][lane];
      ic[b2*39 + lane] = (lane < vlen) ? 0 : -1;
    }
    if (bv && lane == 0) vl[b2] = vlen;
  }
  __threadfence();
  grid.sync();

  // ---- phase 3: map LDS pidx through LUT, single output write ----
  if (tid < NCH) slut[tid] = ws[WS_LUT + b*NCH + tid];
  __syncthreads();
#pragma unroll
  for (int r = 0; r < 3; r++)
    for (int ck = 0; ck < 3; ck++) {
      int x = ck*256 + tid;
      out[(size_t)b*HW + (size_t)(y0b + r)*Ww + x] = slut[s_pidx8[r*Ww + x]];
    }
}

// ===================== fallback: proven R5 4-kernel path =====================
__global__ void k_zero(int* __restrict__ p, int n) {
  for (int i = threadIdx.x; i < n; i += 256) p[i] = 0;
}

__global__ __launch_bounds__(256) void k_fuse(
    const float* __restrict__ sem, const float* __restrict__ roi,
    const float* __restrict__ bbx, const int* __restrict__ cls,
    int* __restrict__ out_pred, int* __restrict__ g_hist, int* __restrict__ g_scount)
{
  __shared__ InstP spar[Nn];
  __shared__ int s_all[NKEY];
  __shared__ unsigned s_rel;

  const int bid = blockIdx.x;
  const int y   = bid % Hh;
  const int b   = bid / Hh;
  const int tid = threadIdx.x;

  if (tid == 0) s_rel = 0u;
  for (int i = tid; i < NKEY; i += 256) s_all[i] = 0;
  if (tid < Nn) {
    setup_inst(b, tid, bbx, cls, spar);
    const InstP p = spar[tid];
    bool rowi = (y >= p.y0) && (y < p.y1r);
    bool rowm = (y >= p.ys) && (y < p.ye);
    if (rowi || rowm) atomicOr(&s_rel, 1u << tid);
  }
  __syncthreads();

  const double EPS = (sigd(NEGD) + sigd(NEGD)) * (NEGD + NEGD);
  const float* base = sem + (size_t)b*Cch*HW + (size_t)y*Ww;

  float ch0[Cch], ch1[Cch], ch2[Cch];
#pragma unroll
  for (int c = 0; c < Cch; c++) ch0[c] = base[(size_t)c*HW + tid];
#pragma unroll
  for (int c = 0; c < Cch; c++) ch1[c] = base[(size_t)c*HW + tid + 256];
#pragma unroll
  for (int c = 0; c < Cch; c++) ch2[c] = base[(size_t)c*HW + tid + 512];

  const unsigned rel = s_rel;
  int smp, pidx;
  pidx = fuse_px(y, tid, ch0, rel, spar, roi, EPS, &smp);
  out_pred[(size_t)b*HW + (size_t)y*Ww + tid] = pidx;
  atomicAdd(&s_all[(pidx >= NSs) ? ((pidx - NSs)*Cch + smp) : (Nn*Cch + pidx)], 1);
  pidx = fuse_px(y, tid + 256, ch1, rel, spar, roi, EPS, &smp);
  out_pred[(size_t)b*HW + (size_t)y*Ww + tid + 256] = pidx;
  atomicAdd(&s_all[(pidx >= NSs) ? ((pidx - NSs)*Cch + smp) : (Nn*Cch + pidx)], 1);
  pidx = fuse_px(y, tid + 512, ch2, rel, spar, roi, EPS, &smp);
  out_pred[(size_t)b*HW + (size_t)y*Ww + tid + 512] = pidx;
  atomicAdd(&s_all[(pidx >= NSs) ? ((pidx - NSs)*Cch + smp) : (Nn*Cch + pidx)], 1);

  __syncthreads();
  for (int i = tid; i < NKEY; i += 256) {
    int v = s_all[i];
    if (v) {
      if (i < Nn*Cch) atomicAdd(&g_hist[b*Nn*Cch + i], v);
      else            atomicAdd(&g_scount[b*NSs + (i - Nn*Cch)], v);
    }
  }
}

__global__ __launch_bounds__(128) void k_post(
    const int* __restrict__ g_hist, const int* __restrict__ g_scount,
    const int* __restrict__ cls, int* __restrict__ lut,
    int* __restrict__ out_tail)
{
  __shared__ int sh[Bb*Nn*Cch];
  __shared__ int spc_s[Bb][NSs];
  __shared__ int pcs[Bb][40];
  const int t = threadIdx.x;
  for (int i = t; i < Bb*Nn*Cch; i += 128) sh[i] = g_hist[i];
  if (t < Bb*NSs) spc_s[t/NSs][t%NSs] = g_scount[t];
  __syncthreads();

  const int b    = t >> 6;
  const int lane = t & 63;
  const bool act = lane < Nn;

  int total = 0, mi = 0, mx = -1, tmp = 0;
  bool br2 = false, kept = false;
  if (act) {
    const int* hb = sh + b*Nn*Cch + lane*Cch;
#pragma unroll
    for (int c = 0; c < Cch; c++) { int v = hb[c]; total += v; if (v > mx) { mx = v; mi = c; } }
    tmp = cls[b*Nn + lane] + NSs;
    bool present = total > 0;
    bool b1 = (mi == tmp);
    br2  = (!b1) && (2*mx >= total) && (mi < NSs) && present;
    kept = present && !br2;
    if (br2) atomicAdd(&spc_s[b][mi], total);
  }
  __syncthreads();

  unsigned mask6 = (unsigned)(__ballot(lane < NSs && spc_s[b][lane] > 0) & 0x3Full);
  int nstuff = __popc(mask6);
  unsigned kmask = (unsigned)(__ballot(act && kept) & 0xFFFFFFFFull);
  int nk = __popc(kmask);
  int vlen = 1 + nstuff + nk;

  if (lane < NSs) lut[b*NCH + lane] = __popc(mask6 & ((1u << lane) - 1)) + 1;
  if (act) {
    int rk     = __popc(kmask & ((1u << lane) - 1));
    int srk_mi = __popc(mask6 & ((1u << mi) - 1));
    lut[b*NCH + NSs + lane] = kept ? (1 + nstuff + rk) : (br2 ? srk_mi + 1 : 0);
  }

  if (lane < 39) pcs[b][lane] = -1;
  __syncthreads();
  if (lane == 0) pcs[b][0] = 255;
  if (lane < NSs && ((mask6 >> lane) & 1))
    pcs[b][1 + __popc(mask6 & ((1u << lane) - 1))] = lane;
  if (act && kept)
    pcs[b][1 + nstuff + __popc(kmask & ((1u << lane) - 1))] = tmp;
  __syncthreads();

  int* pc = out_tail;
  int* ic = out_tail + Bb*39;
  int* vl = out_tail + 2*Bb*39;
  if (lane < 39) {
    pc[b*39 + lane] = pcs[b][lane];
    ic[b*39 + lane] = (lane < vlen) ? 0 : -1;
  }
  if (lane == 0) vl[b] = vlen;
}

__global__ __launch_bounds__(256) void k_seam(int* __restrict__ pred, const int* __restrict__ lut)
{
  __shared__ int slut[Bb*NCH];
  int tid = threadIdx.x;
  if (tid < Bb*NCH) slut[tid] = lut[tid];
  __syncthreads();
  size_t i = ((size_t)blockIdx.x*256 + tid) * 4;
  int b = (int)(i / HW);
  int4 v = *reinterpret_cast<int4*>(pred + i);
  int base = b*NCH;
  v.x = slut[base + v.x];
  v.y = slut[base + v.y];
  v.z = slut[base + v.z];
  v.w = slut[base + v.w];
  *reinterpret_cast<int4*>(pred + i) = v;
}

extern "C" void kernel_launch(void* const* d_in, const int* in_sizes, int n_in,
                              void* d_out, int out_size, void* d_ws, size_t ws_size,
                              hipStream_t stream)
{
  const float* sem = (const float*)d_in[0];
  const float* roi = (const float*)d_in[1];
  const float* bbx = (const float*)d_in[2];
  const int*   cls = (const int*)d_in[3];
  int* out = (int*)d_out;
  int* wsI = (int*)d_ws;

  // coop path: validated, error-checked (R3 failed silently — never again).
  // Decision is deterministic per process: same work every call.
  int maxB = 0;
  hipError_t e = hipOccupancyMaxActiveBlocksPerMultiprocessor(
      &maxB, (const void*)k_all, 256, 0);
  bool ok = (e == hipSuccess) && (maxB >= 2) && (ws_size >= (size_t)(WS_LUT + Bb*NCH)*4);
  if (ok) {
    void* args[] = { (void*)&sem, (void*)&roi, (void*)&bbx, (void*)&cls,
                     (void*)&out, (void*)&wsI };
    ok = hipLaunchCooperativeKernel((const void*)k_all, dim3(512), dim3(256),
                                    args, 0, stream) == hipSuccess;
  }
  if (!ok) {
    int* g_hist   = wsI;                        // Bb*Nn*Cch = 640
    int* g_scount = g_hist + Bb*Nn*Cch;         // Bb*NSs   = 12
    int* lut      = g_scount + Bb*NSs;          // Bb*NCH   = 76
    k_zero<<<1, 256, 0, stream>>>(g_hist, Bb*Nn*Cch + Bb*NSs);
    k_fuse<<<dim3(Bb*Hh), 256, 0, stream>>>(sem, roi, bbx, cls, out, g_hist, g_scount);
    k_post<<<1, 128, 0, stream>>>(g_hist, g_scount, cls, lut, out + (size_t)Bb*HW);
    k_seam<<<dim3((Bb*HW)/(256*4)), 256, 0, stream>>>(out, lut);
  }
}

// Round 7
// 111.972 us; speedup vs baseline: 3.4281x; 3.4281x over previous
//
#include <hip/hip_runtime.h>
#include <math.h>

#define NSs 6
#define NTs 4
#define Bb  2
#define Nn  32
#define Hh  768
#define Ww  768
#define Rr  28
#define Cch 10
#define NCH 38
#define HW  (Hh*Ww)
#define NEGD (-100.0)
#define NKEY (Nn*Cch + NSs)   // 326: 320 inst-hist keys + 6 stuff counts

struct InstP {
  int y0, x0, y1r, x1r;   // inst box [y0,y1r) x [x0,x1r)
  int ys, ye, xs, xe;     // mask box
  float sc_y, sc_x;       // 28.f/h, 28.f/w
  int tc;                 // NS + cls
  int mskoff;             // offset of selected 28x28 mask
};

__device__ __forceinline__ double sigd(double x) { return 1.0 / (1.0 + exp(-x)); }

// proven fuse+argmax core (bit-exact R1..R6). ch[] constant-indexed after inline.
__device__ __forceinline__ int fuse_px(
    int y, int x, const float (&ch)[Cch], unsigned rel,
    const InstP* __restrict__ spar, const float* __restrict__ roi,
    double EPS, int* smp_out)
{
  int smp = 0; float smv = ch[0];
#pragma unroll
  for (int c = 1; c < Cch; c++) if (ch[c] > smv) { smv = ch[c]; smp = c; }
  *smp_out = smp;

  double m = (double)ch[0]; int pidx = 0;
#pragma unroll
  for (int c = 1; c < NSs; c++) { double v = (double)ch[c]; if (v > m) { m = v; pidx = c; } }

  int next_ch = NSs;
  while (rel) {
    int n = __ffs(rel) - 1; rel &= rel - 1;
    int chn_ = NSs + n;
    if (chn_ > next_ch && EPS > m) { m = EPS; pidx = next_ch; }
    next_ch = chn_ + 1;
    const InstP p = spar[n];
    bool in_i = (y >= p.y0) && (y < p.y1r) && (x >= p.x0) && (x < p.x1r);
    bool in_m = (y >= p.ys) && (y < p.ye)  && (x >= p.xs) && (x < p.xe);
    bool in_any = in_i || in_m;
    if (__any(in_any)) {
      if (in_any) {
        // select chain (NOT ch[p.tc]): dynamic reg-array indexing -> scratch
        int tcl = p.tc;
        float tl = (tcl == 6) ? ch[6] : (tcl == 7) ? ch[7] : (tcl == 8) ? ch[8] : ch[9];
        double iv = in_i ? (double)tl : NEGD;
        double mv = NEGD;
        if (in_m) {
          double syv = ((double)(y - p.y0) + 0.5) * (double)p.sc_y - 0.5;
          double sxv = ((double)(x - p.x0) + 0.5) * (double)p.sc_x - 0.5;
          syv = fmin(fmax(syv, 0.0), 27.0);
          sxv = fmin(fmax(sxv, 0.0), 27.0);
          int iy0 = (int)syv, ix0 = (int)sxv;
          int iy1 = min(iy0 + 1, 27), ix1 = min(ix0 + 1, 27);
          double wy = syv - (double)iy0, wx = sxv - (double)ix0;
          const float* mp = roi + p.mskoff;
          double m00 = (double)mp[iy0*Rr + ix0];
          double m01 = (double)mp[iy0*Rr + ix1];
          double m10 = (double)mp[iy1*Rr + ix0];
          double m11 = (double)mp[iy1*Rr + ix1];
          double c0 = m00*(1.0 - wy) + m10*wy;
          double c1 = m01*(1.0 - wy) + m11*wy;
          mv = c0*(1.0 - wx) + c1*wx;
        }
        double s2 = iv + mv;
        // prune: val = s*s2, s in (0,2]; if fmax(2*s2,0) <= m, val>m impossible
        if (fmax(2.0*s2, 0.0) > m) {
          double val = (sigd(iv) + sigd(mv)) * s2;
          if (val > m) { m = val; pidx = chn_; }
        }
      } else {
        if (EPS > m) { m = EPS; pidx = chn_; }
      }
    } else {
      if (EPS > m) { m = EPS; pidx = chn_; }
    }
  }
  if (next_ch < NCH && EPS > m) { m = EPS; pidx = next_ch; }
  return pidx;
}

__device__ __forceinline__ void setup_inst(
    int b, int tid, const float* __restrict__ bbx, const int* __restrict__ cls,
    InstP* spar)
{
  const int n = tid;
  const float* bbp = bbx + ((size_t)b*Nn + n)*4;
  float f0 = bbp[0], f1 = bbp[1], f2 = bbp[2], f3 = bbp[3];
  int y0 = (int)floorf(f0), x0 = (int)floorf(f1);
  int y1 = (int)floorf(f2), x1 = (int)floorf(f3);
  int y1r = (int)(rintf(f2) + 1.0f);   // jnp.round = half-to-even
  int x1r = (int)(rintf(f3) + 1.0f);
  float hh = fmaxf((float)(y1 - y0 + 1), 1.0f);
  float wd = fmaxf((float)(x1 - x0 + 1), 1.0f);
  InstP p;
  p.y0 = y0; p.x0 = x0; p.y1r = y1r; p.x1r = x1r;
  p.ys = max(y0, 0); p.ye = min(y1 + 1, Hh);
  p.xs = max(x0, 0); p.xe = min(x1 + 1, Ww);
  p.sc_y = 28.0f / hh; p.sc_x = 28.0f / wd;
  int cl = cls[b*Nn + n];
  p.tc = NSs + cl;
  p.mskoff = (((b*Nn + n)*NTs) + cl)*Rr*Rr;
  spar[n] = p;
}

__global__ void k_zero(int* __restrict__ p, int n) {
  for (int i = threadIdx.x; i < n; i += 256) p[i] = 0;
}

// grid = B*H = 1536 full-row blocks (load-uniform); 256 thr x 3 chunks.
// Per-WAVE-WINDOW rel gating: one ballot per 64-px window cuts the per-pixel
// instance loop ~5x vs row-level rel (R2: ~500 instr/px even for empty pixels).
// Register budget capped at cur[10]+nxt[10] (R6 spill post-mortem: 60 floats -> scratch).
__global__ __launch_bounds__(256) void k_fuse(
    const float* __restrict__ sem, const float* __restrict__ roi,
    const float* __restrict__ bbx, const int* __restrict__ cls,
    int* __restrict__ out_pred, int* __restrict__ g_hist, int* __restrict__ g_scount)
{
  __shared__ InstP spar[Nn];
  __shared__ int s_all[NKEY];
  __shared__ unsigned s_rel;
  __shared__ int s_xlo[Nn], s_xhi[Nn];

  const int bid  = blockIdx.x;
  const int y    = bid % Hh;
  const int b    = bid / Hh;
  const int tid  = threadIdx.x;
  const int lane = tid & 63;

  if (tid == 0) s_rel = 0u;
  for (int i = tid; i < NKEY; i += 256) s_all[i] = 0;
  if (tid < Nn) {
    setup_inst(b, tid, bbx, cls, spar);
    const InstP p = spar[tid];
    s_xlo[tid] = min(p.x0, p.xs);        // union x-interval (conservative gate)
    s_xhi[tid] = max(p.x1r, p.xe);
    bool rowi = (y >= p.y0) && (y < p.y1r);
    bool rowm = (y >= p.ys) && (y < p.ye);
    if (rowi || rowm) atomicOr(&s_rel, 1u << tid);
  }
  __syncthreads();

  const double EPS = (sigd(NEGD) + sigd(NEGD)) * (NEGD + NEGD);
  const float* base = sem + (size_t)b*Cch*HW + (size_t)y*Ww;

  // per-lane gating registers: lane l (l<32) watches instance l
  const int  li   = lane & 31;
  const int  gxlo = s_xlo[li];
  const int  gxhi = s_xhi[li];
  const bool grow = (lane < 32) && ((s_rel >> li) & 1u);

  float cur[Cch], nxt[Cch];
#pragma unroll
  for (int c = 0; c < Cch; c++) cur[c] = base[(size_t)c*HW + tid];

  for (int ck = 0; ck < 3; ck++) {
    const int x = ck*256 + tid;
    if (ck < 2) {
#pragma unroll
      for (int c = 0; c < Cch; c++) nxt[c] = base[(size_t)c*HW + x + 256];
    }
    const int xa = x & ~63;   // wave's 64-px window base (uniform per wave)
    unsigned relw = (unsigned)__ballot(grow && (gxlo < xa + 64) && (gxhi > xa));

    int smp;
    int pidx = fuse_px(y, x, cur, relw, spar, roi, EPS, &smp);
    out_pred[(size_t)b*HW + (size_t)y*Ww + x] = pidx;
    atomicAdd(&s_all[(pidx >= NSs) ? ((pidx - NSs)*Cch + smp) : (Nn*Cch + pidx)], 1);

    if (ck < 2) {
#pragma unroll
      for (int c = 0; c < Cch; c++) cur[c] = nxt[c];
    }
  }

  __syncthreads();
  for (int i = tid; i < NKEY; i += 256) {
    int v = s_all[i];
    if (v) {
      if (i < Nn*Cch) atomicAdd(&g_hist[b*Nn*Cch + i], v);
      else            atomicAdd(&g_scount[b*NSs + (i - Nn*Cch)], v);
    }
  }
}

// 1 block x 128 threads (wave b = batch b); ballot+popcount ranks, no scratch.
__global__ __launch_bounds__(128) void k_post(
    const int* __restrict__ g_hist, const int* __restrict__ g_scount,
    const int* __restrict__ cls, int* __restrict__ lut,
    int* __restrict__ out_tail)
{
  __shared__ int sh[Bb*Nn*Cch];
  __shared__ int spc_s[Bb][NSs];
  __shared__ int pcs[Bb][40];
  const int t = threadIdx.x;
  for (int i = t; i < Bb*Nn*Cch; i += 128) sh[i] = g_hist[i];
  if (t < Bb*NSs) spc_s[t/NSs][t%NSs] = g_scount[t];
  __syncthreads();

  const int b    = t >> 6;
  const int lane = t & 63;
  const bool act = lane < Nn;

  int total = 0, mi = 0, mx = -1, tmp = 0;
  bool br2 = false, kept = false;
  if (act) {
    const int* hb = sh + b*Nn*Cch + lane*Cch;
#pragma unroll
    for (int c = 0; c < Cch; c++) { int v = hb[c]; total += v; if (v > mx) { mx = v; mi = c; } }
    tmp = cls[b*Nn + lane] + NSs;
    bool present = total > 0;
    bool b1 = (mi == tmp);
    br2  = (!b1) && (2*mx >= total) && (mi < NSs) && present;
    kept = present && !br2;
    if (br2) atomicAdd(&spc_s[b][mi], total);
  }
  __syncthreads();

  unsigned mask6 = (unsigned)(__ballot(lane < NSs && spc_s[b][lane] > 0) & 0x3Full);
  int nstuff = __popc(mask6);
  unsigned kmask = (unsigned)(__ballot(act && kept) & 0xFFFFFFFFull);
  int nk = __popc(kmask);
  int vlen = 1 + nstuff + nk;

  if (lane < NSs) lut[b*NCH + lane] = __popc(mask6 & ((1u << lane) - 1)) + 1; // absent: unused
  if (act) {
    int rk     = __popc(kmask & ((1u << lane) - 1));
    int srk_mi = __popc(mask6 & ((1u << mi) - 1));
    lut[b*NCH + NSs + lane] = kept ? (1 + nstuff + rk) : (br2 ? srk_mi + 1 : 0);
  }

  if (lane < 39) pcs[b][lane] = -1;
  __syncthreads();
  if (lane == 0) pcs[b][0] = 255;
  if (lane < NSs && ((mask6 >> lane) & 1))
    pcs[b][1 + __popc(mask6 & ((1u << lane) - 1))] = lane;
  if (act && kept)
    pcs[b][1 + nstuff + __popc(kmask & ((1u << lane) - 1))] = tmp;
  __syncthreads();

  int* pc = out_tail;                  // po_cls   [Bb][39]
  int* ic = out_tail + Bb*39;          // iscrowd  [Bb][39]
  int* vl = out_tail + 2*Bb*39;        // valid_len[Bb]
  if (lane < 39) {
    pc[b*39 + lane] = pcs[b][lane];
    ic[b*39 + lane] = (lane < vlen) ? 0 : -1;
  }
  if (lane == 0) vl[b] = vlen;
}

__global__ __launch_bounds__(256) void k_seam(int* __restrict__ pred, const int* __restrict__ lut)
{
  __shared__ int slut[Bb*NCH];
  int tid = threadIdx.x;
  if (tid < Bb*NCH) slut[tid] = lut[tid];
  __syncthreads();
  size_t i = ((size_t)blockIdx.x*256 + tid) * 4;
  int b = (int)(i / HW);   // HW divisible by 4: no straddle
  int4 v = *reinterpret_cast<int4*>(pred + i);
  int base = b*NCH;
  v.x = slut[base + v.x];
  v.y = slut[base + v.y];
  v.z = slut[base + v.z];
  v.w = slut[base + v.w];
  *reinterpret_cast<int4*>(pred + i) = v;
}

extern "C" void kernel_launch(void* const* d_in, const int* in_sizes, int n_in,
                              void* d_out, int out_size, void* d_ws, size_t ws_size,
                              hipStream_t stream)
{
  const float* sem = (const float*)d_in[0];
  const float* roi = (const float*)d_in[1];
  const float* bbx = (const float*)d_in[2];
  const int*   cls = (const int*)d_in[3];
  int* out = (int*)d_out;

  int* g_hist   = (int*)d_ws;                 // Bb*Nn*Cch = 640
  int* g_scount = g_hist + Bb*Nn*Cch;         // Bb*NSs   = 12
  int* lut      = g_scount + Bb*NSs;          // Bb*NCH   = 76

  k_zero<<<1, 256, 0, stream>>>(g_hist, Bb*Nn*Cch + Bb*NSs);
  k_fuse<<<dim3(Bb*Hh), 256, 0, stream>>>(sem, roi, bbx, cls, out, g_hist, g_scount);
  k_post<<<1, 128, 0, stream>>>(g_hist, g_scount, cls, lut, out + (size_t)Bb*HW);
  k_seam<<<dim3((Bb*HW)/(256*4)), 256, 0, stream>>>(out, lut);
}